// Round 8
// baseline (18.714 us; speedup 1.0000x reference)
//
#include <hip/hip_runtime.h>
#include <math.h>

typedef float f32x4 __attribute__((ext_vector_type(4)));

__device__ __forceinline__ float frcp(float x) { return __builtin_amdgcn_rcpf(x); }

// SPU(x) = x^2 - 0.5 (x>=0), 1/(1+e^x) - 1 (x<0); grad = 2x (x>=0), -e^x/(1+e^x)^2 (x<0).
// Case-resolved corner evaluation:
//   neg   (u<0):          nl = chord@u  = su (guard err ~4e-7), nu = tangent@l = TL
//   pos   (l>0):          nl = TL,                              nu = chord@u  = su
//   mixed normal (su>sl): nl = argmin-area line @ its corner,   nu = su
//   mixed small:          nl = same,                            nu = sl
__device__ __forceinline__ void spu_bounds(float l, float u, float& nl, float& nu) {
    const float mid = 0.5f * (l + u);
    const float dlu = u - l;                    // >= 0

    const float e_l = __expf(l);
    const float e_u = __expf(u);
    const float e_m = __expf(mid);
    const float r_l = frcp(1.0f + e_l);
    const float r_u = frcp(1.0f + e_u);
    const float r_m = frcp(1.0f + e_m);
    const float rl0 = frcp(1e-8f - l);          // chord l->0 guard

    const bool mpos = (mid >= 0.0f);
    const float sl = (l >= 0.0f) ? fmaf(l, l, -0.5f) : (r_l - 1.0f);
    const float su = (u >= 0.0f) ? fmaf(u, u, -0.5f) : (r_u - 1.0f);
    const float sm = mpos ? fmaf(mid, mid, -0.5f) : (r_m - 1.0f);
    // gmh = -0.5 * spu_grad(mid); for mid <= -87 e_m underflows to 0 -> gmh = 0 (matches ref clamp)
    const float gmh = mpos ? (-mid) : (0.5f * e_m * r_m * r_m);

    const float TL = fmaf(gmh, dlu, sm);        // tangent at mid, evaluated at l

    const bool neg    = (u < 0.0f);
    const bool pos    = (!neg) && (l > 0.0f);
    const bool normal = (!neg) && (!pos) && (su > sl);

    // mixed lower-bound candidates, each evaluated at its active corner:
    const float a1 = (-0.5f - sl) * rl0;        // chord l->0 slope (<= 0)
    const float n1 = fmaf(a1, dlu, sl);         // chord(l->0) @ u
    const float p  = fmaf(0.25f * u, u, 0.5f);
    const float n2 = fmaf(u, l, -p);            // tangent@u/2 (slope u>=0) @ l

    // area argmin via y_i = a_i*(l+u) + 2*b_i  (ar_i = -dlu*y_i; first strict-max of y)
    const float x1 = n1 + sl;                   // = a1*dlu + 2*sl
    const float x2 = fmaf(u, fmaf(0.5f, u, l), -1.0f);   // = u^2/2 + u*l - 1

    const bool  c1   = (x1 > -1.0f);
    const float nl01 = c1 ? n1 : -0.5f;
    const float xb   = c1 ? x1 : -1.0f;
    const bool  c2   = normal && (x2 > xb);
    const float nlm  = c2 ? n2 : nl01;

    nl = neg ? su : (pos ? TL : nlm);
    nu = neg ? TL : ((pos || normal) ? su : sl);
}

__global__ void __launch_bounds__(256) spu_pointwise_kernel(
        const float* __restrict__ l, const float* __restrict__ u,
        float* __restrict__ out_nl, float* __restrict__ out_nu,
        int n4, int n) {
    const int tid = blockIdx.x * blockDim.x + threadIdx.x;
    const int stride = gridDim.x * blockDim.x;

    const f32x4* __restrict__ l4 = reinterpret_cast<const f32x4*>(l);
    const f32x4* __restrict__ u4 = reinterpret_cast<const f32x4*>(u);
    f32x4* __restrict__ nl4 = reinterpret_cast<f32x4*>(out_nl);
    f32x4* __restrict__ nu4 = reinterpret_cast<f32x4*>(out_nu);

    for (int i = tid; i < n4; i += stride) {
        // NT loads: read-once streams, don't allocate L2 (leave L2 for write buffering)
        const f32x4 lv = __builtin_nontemporal_load(l4 + i);
        const f32x4 uv = __builtin_nontemporal_load(u4 + i);
        float a0, b0, a1, b1, a2, b2, a3, b3;
        spu_bounds(lv.x, uv.x, a0, b0);
        spu_bounds(lv.y, uv.y, a1, b1);
        spu_bounds(lv.z, uv.z, a2, b2);
        spu_bounds(lv.w, uv.w, a3, b3);
        f32x4 a, b;
        a.x = a0; a.y = a1; a.z = a2; a.w = a3;
        b.x = b0; b.y = b1; b.z = b2; b.w = b3;
        nl4[i] = a;                    // plain stores: L2 write-buffers the output streams
        nu4[i] = b;
    }

    // scalar tail (n % 4 != 0)
    for (int i = n4 * 4 + tid; i < n; i += stride) {
        spu_bounds(l[i], u[i], out_nl[i], out_nu[i]);
    }
}

extern "C" void kernel_launch(void* const* d_in, const int* in_sizes, int n_in,
                              void* d_out, int out_size, void* d_ws, size_t ws_size,
                              hipStream_t stream) {
    const float* l = (const float*)d_in[0];
    const float* u = (const float*)d_in[1];
    float* out = (float*)d_out;

    const int n = in_sizes[0];          // 64 * 65536 = 4194304
    float* out_nl = out;                // first output, flat
    float* out_nu = out + n;            // second output, flat

    const int n4 = n / 4;
    const int block = 256;
    int grid = (n4 + block - 1) / block;    // 4096 for n=4194304: 1 float4/thread
    if (grid > 8192) grid = 8192;           // grid-stride beyond this
    if (grid < 1) grid = 1;

    spu_pointwise_kernel<<<grid, block, 0, stream>>>(l, u, out_nl, out_nu, n4, n);
}

// Round 9
// 14.275 us; speedup vs baseline: 1.3110x; 1.3110x over previous
//
#include <hip/hip_runtime.h>
#include <math.h>

typedef float f32x4 __attribute__((ext_vector_type(4)));

__device__ __forceinline__ float frcp(float x) { return __builtin_amdgcn_rcpf(x); }

// SPU(x) = x^2 - 0.5 (x>=0), 1/(1+e^x) - 1 (x<0); grad = 2x (x>=0), -e^x/(1+e^x)^2 (x<0).
// Case-resolved corner evaluation (see R6 derivation).
__device__ __forceinline__ void spu_bounds(float l, float u, float& nl, float& nu) {
    const float mid = 0.5f * (l + u);
    const float dlu = u - l;                    // >= 0

    const float e_l = __expf(l);
    const float e_u = __expf(u);
    const float e_m = __expf(mid);
    const float r_l = frcp(1.0f + e_l);
    const float r_u = frcp(1.0f + e_u);
    const float r_m = frcp(1.0f + e_m);
    const float rl0 = frcp(1e-8f - l);          // chord l->0 guard

    const bool mpos = (mid >= 0.0f);
    const float sl = (l >= 0.0f) ? fmaf(l, l, -0.5f) : (r_l - 1.0f);
    const float su = (u >= 0.0f) ? fmaf(u, u, -0.5f) : (r_u - 1.0f);
    const float sm = mpos ? fmaf(mid, mid, -0.5f) : (r_m - 1.0f);
    const float gmh = mpos ? (-mid) : (0.5f * e_m * r_m * r_m);   // -0.5*grad(mid)

    const float TL = fmaf(gmh, dlu, sm);        // tangent at mid, evaluated at l

    const bool neg    = (u < 0.0f);
    const bool pos    = (!neg) && (l > 0.0f);
    const bool normal = (!neg) && (!pos) && (su > sl);

    const float a1 = (-0.5f - sl) * rl0;        // chord l->0 slope
    const float n1 = fmaf(a1, dlu, sl);         // chord(l->0) @ u
    const float p  = fmaf(0.25f * u, u, 0.5f);
    const float n2 = fmaf(u, l, -p);            // tangent@u/2 @ l

    const float x1 = n1 + sl;                   // area-argmin scores
    const float x2 = fmaf(u, fmaf(0.5f, u, l), -1.0f);

    const bool  c1   = (x1 > -1.0f);
    const float nl01 = c1 ? n1 : -0.5f;
    const float xb   = c1 ? x1 : -1.0f;
    const bool  c2   = normal && (x2 > xb);
    const float nlm  = c2 ? n2 : nl01;

    nl = neg ? su : (pos ? TL : nlm);
    nu = neg ? TL : ((pos || normal) ? su : sl);
}

__device__ __forceinline__ void spu_bounds4(const f32x4 lv, const f32x4 uv,
                                            f32x4& a, f32x4& b) {
    float a0, b0, a1, b1, a2, b2, a3, b3;
    spu_bounds(lv.x, uv.x, a0, b0);
    spu_bounds(lv.y, uv.y, a1, b1);
    spu_bounds(lv.z, uv.z, a2, b2);
    spu_bounds(lv.w, uv.w, a3, b3);
    a.x = a0; a.y = a1; a.z = a2; a.w = a3;
    b.x = b0; b.y = b1; b.z = b2; b.w = b3;
}

__global__ void __launch_bounds__(256) spu_pointwise_kernel(
        const float* __restrict__ l, const float* __restrict__ u,
        float* __restrict__ out_nl, float* __restrict__ out_nu,
        int n4, int n) {
    const int tid = blockIdx.x * blockDim.x + threadIdx.x;
    const int stride = gridDim.x * blockDim.x;
    const int pairs = n4 >> 1;

    const f32x4* __restrict__ l4 = reinterpret_cast<const f32x4*>(l);
    const f32x4* __restrict__ u4 = reinterpret_cast<const f32x4*>(u);
    f32x4* __restrict__ nl4 = reinterpret_cast<f32x4*>(out_nl);
    f32x4* __restrict__ nu4 = reinterpret_cast<f32x4*>(out_nu);

    // 2 independent float4 streams per thread: PLAIN loads (inputs are
    // L2/L3-resident -> cache hits), NT stores (write-once streams).
    // All 4 loads issue before either compute chain -> 2x memory parallelism.
    for (int i = tid; i < pairs; i += stride) {
        const int j = i + pairs;
        const f32x4 lv0 = l4[i];
        const f32x4 uv0 = u4[i];
        const f32x4 lv1 = l4[j];
        const f32x4 uv1 = u4[j];
        f32x4 a0, b0, a1, b1;
        spu_bounds4(lv0, uv0, a0, b0);
        spu_bounds4(lv1, uv1, a1, b1);
        __builtin_nontemporal_store(a0, nl4 + i);
        __builtin_nontemporal_store(b0, nu4 + i);
        __builtin_nontemporal_store(a1, nl4 + j);
        __builtin_nontemporal_store(b1, nu4 + j);
    }

    // odd leftover float4 (if n4 is odd)
    for (int i = 2 * pairs + tid; i < n4; i += stride) {
        const f32x4 lv = l4[i];
        const f32x4 uv = u4[i];
        f32x4 a, b;
        spu_bounds4(lv, uv, a, b);
        __builtin_nontemporal_store(a, nl4 + i);
        __builtin_nontemporal_store(b, nu4 + i);
    }

    // scalar tail (n % 4 != 0)
    for (int i = n4 * 4 + tid; i < n; i += stride) {
        spu_bounds(l[i], u[i], out_nl[i], out_nu[i]);
    }
}

extern "C" void kernel_launch(void* const* d_in, const int* in_sizes, int n_in,
                              void* d_out, int out_size, void* d_ws, size_t ws_size,
                              hipStream_t stream) {
    const float* l = (const float*)d_in[0];
    const float* u = (const float*)d_in[1];
    float* out = (float*)d_out;

    const int n = in_sizes[0];          // 64 * 65536 = 4194304
    float* out_nl = out;                // first output, flat
    float* out_nu = out + n;            // second output, flat

    const int n4 = n / 4;
    const int pairs = n4 / 2;
    const int block = 256;
    int grid = (pairs + block - 1) / block;   // 2048 for n=4194304
    if (grid > 8192) grid = 8192;
    if (grid < 1) grid = 1;

    spu_pointwise_kernel<<<grid, block, 0, stream>>>(l, u, out_nl, out_nu, n4, n);
}